// Round 1
// baseline (399.578 us; speedup 1.0000x reference)
//
#include <hip/hip_runtime.h>
#include <math.h>

#define B_   4
#define N_   2048
#define DIM_ 1024
#define H_   16
#define DH_  64
#define M_   (B_ * N_)          // 8192
#define QKV_ELEMS ((size_t)B_ * H_ * N_ * DH_)   // 8388608

typedef __attribute__((ext_vector_type(8))) short short8;   // 8 bf16 (4 VGPRs)
typedef __attribute__((ext_vector_type(4))) float floatx4;  // MFMA C/D frag

// round-to-nearest-even float -> bf16 bits
static __device__ inline unsigned short f2bf(float f) {
    union { float f; unsigned u; } v; v.f = f;
    unsigned r = (v.u + 0x7fffu + ((v.u >> 16) & 1u)) >> 16;
    return (unsigned short)r;
}

// async global->LDS, 16 B per lane. lds dest = wave-uniform base + lane*16.
static __device__ inline void async_copy16(const void* g, void* l) {
    __builtin_amdgcn_global_load_lds(
        (const __attribute__((address_space(1))) unsigned int*)g,
        (__attribute__((address_space(3))) unsigned int*)l, 16, 0, 0);
}

// ---------------------------------------------------------------------------
// Kernel 0: fp32 -> bf16 convert
// ---------------------------------------------------------------------------
__global__ __launch_bounds__(256) void f32_to_bf16_kernel(
    const float* __restrict__ src, unsigned short* __restrict__ dst, int n8)
{
    int i = blockIdx.x * 256 + threadIdx.x;
    if (i >= n8) return;
    float4 a = ((const float4*)src)[i * 2];
    float4 b = ((const float4*)src)[i * 2 + 1];
    short8 o;
    o[0] = f2bf(a.x); o[1] = f2bf(a.y); o[2] = f2bf(a.z); o[3] = f2bf(a.w);
    o[4] = f2bf(b.x); o[5] = f2bf(b.y); o[6] = f2bf(b.z); o[7] = f2bf(b.w);
    *(short8*)(dst + (size_t)i * 8) = o;
}

// ---------------------------------------------------------------------------
// bf16 MFMA GEMM core (m97 structure): C[m,n] = sum_k A[m,k]*B[n,k]
// ---------------------------------------------------------------------------
#define GEMM_BODY(Aptr, Bptr, K)                                               \
    __shared__ unsigned short As[128 * 32];                                    \
    __shared__ unsigned short Bs[128 * 32];                                    \
    const int tid  = threadIdx.x;                                              \
    const int lane = tid & 63;                                                 \
    const int wv   = tid >> 6;                                                 \
    const int l15  = lane & 15, quad = lane >> 4;                              \
    const int wrow = (wv >> 1) * 64, wcol = (wv & 1) * 64;                     \
    const int m0 = blockIdx.y * 128, n0 = blockIdx.x * 128;                    \
    const int lrow = lane >> 2;                                                \
    const int lkc  = (lane & 3) * 8;                                           \
    const unsigned short* ga0 = Aptr + (size_t)(m0 + wv * 32 + lrow) * K + lkc;\
    const unsigned short* ga1 = ga0 + (size_t)16 * K;                          \
    const unsigned short* gb0 = Bptr + (size_t)(n0 + wv * 32 + lrow) * K + lkc;\
    const unsigned short* gb1 = gb0 + (size_t)16 * K;                          \
    unsigned short* lA0 = &As[wv * 1024];                                      \
    unsigned short* lA1 = lA0 + 512;                                           \
    unsigned short* lB0 = &Bs[wv * 1024];                                      \
    unsigned short* lB1 = lB0 + 512;                                           \
    floatx4 acc[4][4] = {};                                                    \
    for (int k0 = 0; k0 < K; k0 += 32) {                                       \
        __syncthreads();                                                       \
        async_copy16(ga0 + k0, lA0);                                           \
        async_copy16(ga1 + k0, lA1);                                           \
        async_copy16(gb0 + k0, lB0);                                           \
        async_copy16(gb1 + k0, lB1);                                           \
        __syncthreads();                                                       \
        short8 af[4], bf[4];                                                   \
        _Pragma("unroll")                                                      \
        for (int mt = 0; mt < 4; ++mt)                                         \
            af[mt] = *(const short8*)&As[(wrow + mt * 16 + l15) * 32 + quad * 8];\
        _Pragma("unroll")                                                      \
        for (int nt = 0; nt < 4; ++nt)                                         \
            bf[nt] = *(const short8*)&Bs[(wcol + nt * 16 + l15) * 32 + quad * 8];\
        _Pragma("unroll")                                                      \
        for (int mt = 0; mt < 4; ++mt)                                         \
            _Pragma("unroll")                                                  \
            for (int nt = 0; nt < 4; ++nt)                                     \
                acc[mt][nt] = __builtin_amdgcn_mfma_f32_16x16x32_bf16(         \
                    af[mt], bf[nt], acc[mt][nt], 0, 0, 0);                     \
    }

// ---------------------------------------------------------------------------
// Kernel 1: QKV projection, bf16 MFMA. M=8192, N=3072, K=1024.
// Epilogue: q gets noise then *0.125*log2e (attn scale + exp2 fold), bf16.
// k in [B,H,N,DH]; v stored TRANSPOSED [B,H,DH,N] for the attention PV stage.
// ---------------------------------------------------------------------------
__global__ __launch_bounds__(256) void gemm_qkv_bf16(
    const unsigned short* __restrict__ A, const unsigned short* __restrict__ Bm,
    const float* __restrict__ bias, const float* __restrict__ eps,
    const float* __restrict__ temp,
    unsigned short* __restrict__ qb, unsigned short* __restrict__ kb,
    unsigned short* __restrict__ vb)
{
    GEMM_BODY(A, Bm, 1024)

    const float sig = 1.0f / (1.0f + __expf(-temp[0]));
    const float qscale = 0.125f * 1.44269504f;   // 1/sqrt(DH) * log2(e)
#pragma unroll
    for (int mt = 0; mt < 4; ++mt) {
#pragma unroll
        for (int r = 0; r < 4; ++r) {
            const int m  = m0 + wrow + mt * 16 + quad * 4 + r;
            const int b  = m >> 11;
            const int nn = m & 2047;
#pragma unroll
            for (int nt = 0; nt < 4; ++nt) {
                const int n = n0 + wcol + nt * 16 + l15;
                float val = acc[mt][nt][r] + bias[n];
                const int which = n >> 10;   // 0=q 1=k 2=v
                const int d  = n & 1023;
                const int h  = d >> 6;
                const int dd = d & 63;
                const size_t bh = (size_t)(b * H_ + h);
                if (which == 0) {
                    const size_t idx = (bh * N_ + nn) * DH_ + dd;
                    qb[idx] = f2bf((val + eps[idx] * sig) * qscale);
                } else if (which == 1) {
                    kb[(bh * N_ + nn) * DH_ + dd] = f2bf(val);
                } else {
                    vb[(bh * DH_ + dd) * N_ + nn] = f2bf(val);   // transposed
                }
            }
        }
    }
}

// ---------------------------------------------------------------------------
// Kernel 3: output projection, bf16 MFMA. M=8192, N=1024, K=1024. fp32 out.
// ---------------------------------------------------------------------------
__global__ __launch_bounds__(256) void gemm_proj_bf16(
    const unsigned short* __restrict__ A, const unsigned short* __restrict__ Bm,
    const float* __restrict__ bias, float* __restrict__ out)
{
    GEMM_BODY(A, Bm, 1024)

#pragma unroll
    for (int mt = 0; mt < 4; ++mt) {
#pragma unroll
        for (int r = 0; r < 4; ++r) {
            const int m = m0 + wrow + mt * 16 + quad * 4 + r;
#pragma unroll
            for (int nt = 0; nt < 4; ++nt) {
                const int n = n0 + wcol + nt * 16 + l15;
                out[(size_t)m * 1024 + n] = acc[mt][nt][r] + bias[n];
            }
        }
    }
}

// ---------------------------------------------------------------------------
// Kernel 2: flash attention v2.
//  - 2 waves/block, 32 q-rows per wave (64 q/block): FLOP per LDS byte 16->26
//  - KVBLK=32, double-buffered async K/V staging via global_load_lds,
//    ONE __syncthreads per tile (its vmcnt(0) drain is the pipeline wait)
//  - LDS linear + XOR swizzle; global source pre-swizzled (m201/m173 pattern)
//  - swapped QK^T: mfma(K,Q) -> lane holds 4 CONSECUTIVE KEYS for q=l15, so
//    P spills to LDS as 4x ds_write_b64 (packed bf16) instead of 16x b16;
//    PV-side b128 P read unchanged. Row-sum becomes 1 scalar/group.
//  - XCD swizzle: 8 consecutive bh per XCD -> K/V working set = one L2
//  - q pre-scaled by 0.125*log2e, p = exp2(S) directly, no-max softmax.
// ---------------------------------------------------------------------------
__global__ __launch_bounds__(128) void attn_kernel(
    const unsigned short* __restrict__ qb, const unsigned short* __restrict__ kb,
    const unsigned short* __restrict__ vt, unsigned short* __restrict__ attn_out)
{
    __shared__ unsigned short Ks[2][32 * 64];  // [key][d], 128B rows, swz ((row&7)<<4)
    __shared__ unsigned short Vs[2][64 * 32];  // [d][key], 64B rows,  swz ((row&3)<<4)
    __shared__ unsigned short Ps[64 * 40];     // [qrow][key], 80B rows (pad 8)

    const int tid  = threadIdx.x;
    const int lane = tid & 63;
    const int wv   = tid >> 6;      // 0,1
    const int l15  = lane & 15;
    const int quad = lane >> 4;
    const int s7   = l15 & 7;
    const int s3   = l15 & 3;

    // XCD-aware swizzle (bijective: 2048 blocks = 8*256)
    const int f  = blockIdx.y * 32 + blockIdx.x;
    const int L  = (f & 7) * 256 + (f >> 3);
    const int bh = L >> 5;          // 8 consecutive bh per XCD
    const int b  = bh >> 4, h = bh & 15;
    const int q0 = (L & 31) * 64;

    const unsigned short* kb_bh = kb + (size_t)bh * N_ * DH_;
    const unsigned short* vt_bh = vt + (size_t)bh * DH_ * N_;

    // Q fragments: 2 groups of 16 rows x (d0-31, d32-63)
    short8 qf[2][2];
#pragma unroll
    for (int g = 0; g < 2; ++g) {
        const unsigned short* qp =
            qb + ((size_t)bh * N_ + q0 + wv * 32 + g * 16 + l15) * DH_;
        qf[g][0] = *(const short8*)(qp + quad * 8);
        qf[g][1] = *(const short8*)(qp + 32 + quad * 8);
    }

    floatx4 o[2][4] = {};
    float l_part[2] = {0.f, 0.f};

    // staging geometry: thread tid writes physical byte c*2048 + tid*16.
    // K rows = 128B: row = c*16 + (tid>>3), phys slot tid&7, src slot ^(row&7)
    // V rows = 64B:  row = c*32 + (tid>>2), phys slot tid&3, src slot ^(row&3)
    const int kr  = tid >> 3;
    const int kls = (tid & 7) ^ (kr & 7);
    const int vd  = tid >> 2;
    const int vls = (tid & 3) ^ (vd & 3);

#define STAGE(buf, kt)                                                           \
    do {                                                                         \
        _Pragma("unroll")                                                        \
        for (int c = 0; c < 2; ++c) {                                            \
            async_copy16(kb_bh + (size_t)((kt) * 32 + c * 16 + kr) * DH_ + kls * 8, \
                         &Ks[buf][c * 1024 + wv * 512]);                         \
            async_copy16(vt_bh + (size_t)(c * 32 + vd) * N_ + (kt) * 32 + vls * 8,  \
                         &Vs[buf][c * 1024 + wv * 512]);                         \
        }                                                                        \
    } while (0)

    STAGE(0, 0);

#pragma unroll 2
    for (int kt = 0; kt < 64; ++kt) {
        const int cur = kt & 1;
        __syncthreads();                 // vmcnt(0)+lgkmcnt(0) drain + barrier
        if (kt < 63) STAGE(cur ^ 1, kt + 1);   // async, flies under compute

        const unsigned short* Kc = Ks[cur];
        const unsigned short* Vc = Vs[cur];

        // K frags (shared by both q-groups): rows key, k-dim d, swizzled read
        short8 kf[2][2];
#pragma unroll
        for (int nt = 0; nt < 2; ++nt) {
            const int off0 = (nt * 16 + l15) * 64 + (quad ^ s7) * 8;
            kf[nt][0] = *(const short8*)(Kc + off0);
            kf[nt][1] = *(const short8*)(Kc + (off0 ^ 32));
        }
        // V frags: rows d, k-dim keys (32), swizzled read
        short8 vf[4];
#pragma unroll
        for (int dt = 0; dt < 4; ++dt)
            vf[dt] = *(const short8*)(Vc + (dt * 16 + l15) * 32 + (quad ^ s3) * 8);

#pragma unroll
        for (int g = 0; g < 2; ++g) {
            const int prow = wv * 32 + g * 16 + l15;
            floatx4 s[2];
            __builtin_amdgcn_s_setprio(1);
#pragma unroll
            for (int nt = 0; nt < 2; ++nt) {   // SWAPPED: D[key][q]
                floatx4 c = {};
                c = __builtin_amdgcn_mfma_f32_16x16x32_bf16(kf[nt][0], qf[g][0], c, 0, 0, 0);
                c = __builtin_amdgcn_mfma_f32_16x16x32_bf16(kf[nt][1], qf[g][1], c, 0, 0, 0);
                s[nt] = c;
            }
            __builtin_amdgcn_s_setprio(0);

            // p = 2^s; lane holds keys nt*16+quad*4+{0..3} for q = l15
#pragma unroll
            for (int nt = 0; nt < 2; ++nt) {
#pragma unroll
                for (int r = 0; r < 4; ++r)
                    s[nt][r] = __builtin_amdgcn_exp2f(s[nt][r]);
                l_part[g] += (s[nt][0] + s[nt][1]) + (s[nt][2] + s[nt][3]);
                // pack 4 consecutive keys (round-half-up) -> one ds_write_b64
                unsigned w0 = ((__float_as_uint(s[nt][0]) + 0x8000u) >> 16) |
                              ((__float_as_uint(s[nt][1]) + 0x8000u) & 0xffff0000u);
                unsigned w1 = ((__float_as_uint(s[nt][2]) + 0x8000u) >> 16) |
                              ((__float_as_uint(s[nt][3]) + 0x8000u) & 0xffff0000u);
                uint2 wp; wp.x = w0; wp.y = w1;
                *(uint2*)&Ps[prow * 40 + nt * 16 + quad * 4] = wp;
            }
            // same-wave write->read: compiler inserts lgkmcnt wait, no barrier
            const short8 pf = *(const short8*)&Ps[prow * 40 + quad * 8];

            __builtin_amdgcn_s_setprio(1);
#pragma unroll
            for (int dt = 0; dt < 4; ++dt)
                o[g][dt] = __builtin_amdgcn_mfma_f32_16x16x32_bf16(pf, vf[dt], o[g][dt], 0, 0, 0);
            __builtin_amdgcn_s_setprio(0);
        }
    }
#undef STAGE

    // final softmax-denominator reduction: sum over the 4 quad-groups
#pragma unroll
    for (int g = 0; g < 2; ++g) {
        float lsum = l_part[g];
        lsum += __shfl_xor(lsum, 16, 64);
        lsum += __shfl_xor(lsum, 32, 64);
        const float inv = 1.0f / lsum;   // all lanes: denom for q = l15
#pragma unroll
        for (int r = 0; r < 4; ++r) {
            const float invq = __shfl(inv, quad * 4 + r, 64);  // denom for this O row
            const int row = q0 + wv * 32 + g * 16 + quad * 4 + r;
#pragma unroll
            for (int dt = 0; dt < 4; ++dt)
                attn_out[((size_t)b * N_ + row) * DIM_ + h * DH_ + dt * 16 + l15] =
                    f2bf(o[g][dt][r] * invq);
        }
    }
}

// ---------------------------------------------------------------------------
extern "C" void kernel_launch(void* const* d_in, const int* in_sizes, int n_in,
                              void* d_out, int out_size, void* d_ws, size_t ws_size,
                              hipStream_t stream) {
    const float* x      = (const float*)d_in[0];
    const float* qkv_w  = (const float*)d_in[1];
    const float* qkv_b  = (const float*)d_in[2];
    const float* proj_w = (const float*)d_in[3];
    const float* proj_b = (const float*)d_in[4];
    const float* temp   = (const float*)d_in[5];
    const float* eps    = (const float*)d_in[6];
    float* out = (float*)d_out;

    unsigned short* qb   = (unsigned short*)d_ws;          // [B,H,N,DH]
    unsigned short* kb   = qb + QKV_ELEMS;                 // [B,H,N,DH]
    unsigned short* vb   = kb + QKV_ELEMS;                 // [B,H,DH,N] (transposed)
    unsigned short* xb   = vb + QKV_ELEMS;                 // x bf16
    unsigned short* wqb  = xb + QKV_ELEMS;                 // qkv_w bf16
    unsigned short* pwb  = wqb + (size_t)3 * DIM_ * DIM_;  // proj_w bf16
    unsigned short* attn = pwb + (size_t)DIM_ * DIM_;      // attn bf16 [B,N,DIM]

    dim3 blk(256);
    f32_to_bf16_kernel<<<dim3(8388608 / 8 / 256), blk, 0, stream>>>(x, xb, 8388608 / 8);
    f32_to_bf16_kernel<<<dim3(3145728 / 8 / 256), blk, 0, stream>>>(qkv_w, wqb, 3145728 / 8);
    f32_to_bf16_kernel<<<dim3(1048576 / 8 / 256), blk, 0, stream>>>(proj_w, pwb, 1048576 / 8);

    gemm_qkv_bf16<<<dim3(24, 64), blk, 0, stream>>>(xb, wqb, qkv_b, eps, temp,
                                                    qb, kb, vb);
    attn_kernel<<<dim3(32, 64), dim3(128), 0, stream>>>(qb, kb, vb, attn);
    gemm_proj_bf16<<<dim3(8, 64), blk, 0, stream>>>(attn, pwb, proj_b, out);
}

// Round 2
// 395.505 us; speedup vs baseline: 1.0103x; 1.0103x over previous
//
#include <hip/hip_runtime.h>
#include <math.h>

#define B_   4
#define N_   2048
#define DIM_ 1024
#define H_   16
#define DH_  64
#define M_   (B_ * N_)          // 8192
#define QKV_ELEMS ((size_t)B_ * H_ * N_ * DH_)   // 8388608

typedef __attribute__((ext_vector_type(8))) short short8;   // 8 bf16 (4 VGPRs)
typedef __attribute__((ext_vector_type(4))) float floatx4;  // MFMA C/D frag

// round-to-nearest-even float -> bf16 bits
static __device__ inline unsigned short f2bf(float f) {
    union { float f; unsigned u; } v; v.f = f;
    unsigned r = (v.u + 0x7fffu + ((v.u >> 16) & 1u)) >> 16;
    return (unsigned short)r;
}

// pack two f32 -> two bf16 (round-half-up, matches P rounding used before)
static __device__ inline unsigned pkbf(float a, float b) {
    unsigned ua = (__float_as_uint(a) + 0x8000u) >> 16;
    unsigned ub = (__float_as_uint(b) + 0x8000u) & 0xffff0000u;
    return ua | ub;
}

// async global->LDS, 16 B per lane. lds dest = wave-uniform base + lane*16.
static __device__ inline void async_copy16(const void* g, void* l) {
    __builtin_amdgcn_global_load_lds(
        (const __attribute__((address_space(1))) unsigned int*)g,
        (__attribute__((address_space(3))) unsigned int*)l, 16, 0, 0);
}

// ---------------------------------------------------------------------------
// Kernel 0: fp32 -> bf16 convert
// ---------------------------------------------------------------------------
__global__ __launch_bounds__(256) void f32_to_bf16_kernel(
    const float* __restrict__ src, unsigned short* __restrict__ dst, int n8)
{
    int i = blockIdx.x * 256 + threadIdx.x;
    if (i >= n8) return;
    float4 a = ((const float4*)src)[i * 2];
    float4 b = ((const float4*)src)[i * 2 + 1];
    short8 o;
    o[0] = f2bf(a.x); o[1] = f2bf(a.y); o[2] = f2bf(a.z); o[3] = f2bf(a.w);
    o[4] = f2bf(b.x); o[5] = f2bf(b.y); o[6] = f2bf(b.z); o[7] = f2bf(b.w);
    *(short8*)(dst + (size_t)i * 8) = o;
}

// ---------------------------------------------------------------------------
// bf16 MFMA GEMM core (m97 structure): C[m,n] = sum_k A[m,k]*B[n,k]
// ---------------------------------------------------------------------------
#define GEMM_BODY(Aptr, Bptr, K)                                               \
    __shared__ unsigned short As[128 * 32];                                    \
    __shared__ unsigned short Bs[128 * 32];                                    \
    const int tid  = threadIdx.x;                                              \
    const int lane = tid & 63;                                                 \
    const int wv   = tid >> 6;                                                 \
    const int l15  = lane & 15, quad = lane >> 4;                              \
    const int wrow = (wv >> 1) * 64, wcol = (wv & 1) * 64;                     \
    const int m0 = blockIdx.y * 128, n0 = blockIdx.x * 128;                    \
    const int lrow = lane >> 2;                                                \
    const int lkc  = (lane & 3) * 8;                                           \
    const unsigned short* ga0 = Aptr + (size_t)(m0 + wv * 32 + lrow) * K + lkc;\
    const unsigned short* ga1 = ga0 + (size_t)16 * K;                          \
    const unsigned short* gb0 = Bptr + (size_t)(n0 + wv * 32 + lrow) * K + lkc;\
    const unsigned short* gb1 = gb0 + (size_t)16 * K;                          \
    unsigned short* lA0 = &As[wv * 1024];                                      \
    unsigned short* lA1 = lA0 + 512;                                           \
    unsigned short* lB0 = &Bs[wv * 1024];                                      \
    unsigned short* lB1 = lB0 + 512;                                           \
    floatx4 acc[4][4] = {};                                                    \
    for (int k0 = 0; k0 < K; k0 += 32) {                                       \
        __syncthreads();                                                       \
        async_copy16(ga0 + k0, lA0);                                           \
        async_copy16(ga1 + k0, lA1);                                           \
        async_copy16(gb0 + k0, lB0);                                           \
        async_copy16(gb1 + k0, lB1);                                           \
        __syncthreads();                                                       \
        short8 af[4], bf[4];                                                   \
        _Pragma("unroll")                                                      \
        for (int mt = 0; mt < 4; ++mt)                                         \
            af[mt] = *(const short8*)&As[(wrow + mt * 16 + l15) * 32 + quad * 8];\
        _Pragma("unroll")                                                      \
        for (int nt = 0; nt < 4; ++nt)                                         \
            bf[nt] = *(const short8*)&Bs[(wcol + nt * 16 + l15) * 32 + quad * 8];\
        _Pragma("unroll")                                                      \
        for (int mt = 0; mt < 4; ++mt)                                         \
            _Pragma("unroll")                                                  \
            for (int nt = 0; nt < 4; ++nt)                                     \
                acc[mt][nt] = __builtin_amdgcn_mfma_f32_16x16x32_bf16(         \
                    af[mt], bf[nt], acc[mt][nt], 0, 0, 0);                     \
    }

// ---------------------------------------------------------------------------
// Kernel 1: QKV projection, bf16 MFMA. M=8192, N=3072, K=1024.
// Epilogue: q gets noise then *0.125*log2e (attn scale + exp2 fold), bf16.
// k in [B,H,N,DH]; v stored TRANSPOSED [B,H,DH,N] for the attention PV stage.
// ---------------------------------------------------------------------------
__global__ __launch_bounds__(256) void gemm_qkv_bf16(
    const unsigned short* __restrict__ A, const unsigned short* __restrict__ Bm,
    const float* __restrict__ bias, const float* __restrict__ eps,
    const float* __restrict__ temp,
    unsigned short* __restrict__ qb, unsigned short* __restrict__ kb,
    unsigned short* __restrict__ vb)
{
    GEMM_BODY(A, Bm, 1024)

    const float sig = 1.0f / (1.0f + __expf(-temp[0]));
    const float qscale = 0.125f * 1.44269504f;   // 1/sqrt(DH) * log2(e)
#pragma unroll
    for (int mt = 0; mt < 4; ++mt) {
#pragma unroll
        for (int r = 0; r < 4; ++r) {
            const int m  = m0 + wrow + mt * 16 + quad * 4 + r;
            const int b  = m >> 11;
            const int nn = m & 2047;
#pragma unroll
            for (int nt = 0; nt < 4; ++nt) {
                const int n = n0 + wcol + nt * 16 + l15;
                float val = acc[mt][nt][r] + bias[n];
                const int which = n >> 10;   // 0=q 1=k 2=v
                const int d  = n & 1023;
                const int h  = d >> 6;
                const int dd = d & 63;
                const size_t bh = (size_t)(b * H_ + h);
                if (which == 0) {
                    const size_t idx = (bh * N_ + nn) * DH_ + dd;
                    qb[idx] = f2bf((val + eps[idx] * sig) * qscale);
                } else if (which == 1) {
                    kb[(bh * N_ + nn) * DH_ + dd] = f2bf(val);
                } else {
                    vb[(bh * DH_ + dd) * N_ + nn] = f2bf(val);   // transposed
                }
            }
        }
    }
}

// ---------------------------------------------------------------------------
// Kernel 3: output projection, bf16 MFMA. M=8192, N=1024, K=1024. fp32 out.
// ---------------------------------------------------------------------------
__global__ __launch_bounds__(256) void gemm_proj_bf16(
    const unsigned short* __restrict__ A, const unsigned short* __restrict__ Bm,
    const float* __restrict__ bias, float* __restrict__ out)
{
    GEMM_BODY(A, Bm, 1024)

#pragma unroll
    for (int mt = 0; mt < 4; ++mt) {
#pragma unroll
        for (int r = 0; r < 4; ++r) {
            const int m = m0 + wrow + mt * 16 + quad * 4 + r;
#pragma unroll
            for (int nt = 0; nt < 4; ++nt) {
                const int n = n0 + wcol + nt * 16 + l15;
                out[(size_t)m * 1024 + n] = acc[mt][nt][r] + bias[n];
            }
        }
    }
}

// ---------------------------------------------------------------------------
// Kernel 2: flash attention v3 — ZERO LDS, zero barriers.
//  Theory: v2's LDS pipe was ~64% subscribed (20 b128 reads + staging +
//  P round-trip per block-tile vs 155 MFMA cyc) and barrier-coupled.
//  K/V are L2-resident (512 KB/head; FETCH_SIZE proved compulsory-only),
//  so fragments are loaded straight from global (L2) into registers with
//  the same per-lane index pattern as the verified Q load:
//    - 64 q-rows per wave (4 g-groups of 16): total L2 read = 1.07 GB ~ 31 us
//    - K double-buffered in registers (next tile prefetched under compute)
//    - V loaded at tile top, consumed ~300 cyc later (QK+softmax covers it)
//  P never touches memory: swapped-QK output (lane quad Q holds keys
//  16nt+4Q..+3 of q=l15) is rearranged to the PV A-frag (keys 8Q..8Q+7)
//  by a 2-step butterfly on packed bf16 words:
//    out[q1,q0][j1,j0] = in[q0,j1][q1,j0]  (4x shfl_xor + 8x cndmask)
//  Waves fully independent -> compiler emits counted vmcnt, no drain stall.
// ---------------------------------------------------------------------------
__global__ __launch_bounds__(256, 2) void attn_kernel(
    const unsigned short* __restrict__ qb, const unsigned short* __restrict__ kb,
    const unsigned short* __restrict__ vt, unsigned short* __restrict__ attn_out)
{
    const int tid  = threadIdx.x;
    const int lane = tid & 63;
    const int wv   = tid >> 6;      // 0..3, independent waves (no barriers)
    const int l15  = lane & 15;
    const int quad = lane >> 4;
    const int q1   = quad >> 1;     // quad bit 1 (lane bit 32)
    const int q0b  = quad & 1;      // quad bit 0 (lane bit 16)

    // XCD-aware swizzle: 512 blocks = 8 XCDs x 64; 8 consecutive bh per XCD
    // -> per-XCD K/V working set = 8 * 512 KB = 4 MB = one L2.
    const int f  = blockIdx.x;
    const int L  = (f & 7) * 64 + (f >> 3);
    const int bh = L >> 3;
    const int b  = bh >> 4, h = bh & 15;
    const int qbase = (L & 7) * 256 + wv * 64;   // 64 q-rows per wave

    const unsigned short* kb_bh = kb + (size_t)bh * N_ * DH_;
    const unsigned short* vt_bh = vt + (size_t)bh * DH_ * N_;

    // Q fragments: 4 groups of 16 rows x (d0-31, d32-63). (q pre-scaled.)
    short8 qf[4][2];
#pragma unroll
    for (int g = 0; g < 4; ++g) {
        const unsigned short* qp =
            qb + ((size_t)bh * N_ + qbase + g * 16 + l15) * DH_;
        qf[g][0] = *(const short8*)(qp + quad * 8);
        qf[g][1] = *(const short8*)(qp + 32 + quad * 8);
    }

    floatx4 o[4][4] = {};
    float l_part[4] = {0.f, 0.f, 0.f, 0.f};

    // per-lane fragment base pointers (wave-uniform base stays in SGPRs)
    const unsigned short* kA = kb_bh + (size_t)l15 * DH_ + quad * 8;
    const unsigned short* vA = vt_bh + (size_t)l15 * N_ + quad * 8;

    short8 kfA[2][2], kfB[2][2];

#define LOADK(DST, ktn)                                                        \
    do {                                                                       \
        _Pragma("unroll")                                                      \
        for (int nt = 0; nt < 2; ++nt) {                                       \
            _Pragma("unroll")                                                  \
            for (int hh = 0; hh < 2; ++hh)                                     \
                DST[nt][hh] = *(const short8*)(                                \
                    kA + (size_t)((ktn) * 32 + nt * 16) * DH_ + hh * 32);      \
        }                                                                      \
    } while (0)

#define TILE(CUR, NXT, kt, ktn)                                                \
    do {                                                                       \
        short8 vf[4];                                                          \
        _Pragma("unroll")                                                      \
        for (int dt = 0; dt < 4; ++dt)                                         \
            vf[dt] = *(const short8*)(vA + (size_t)dt * 16 * N_ + (kt) * 32);  \
        LOADK(NXT, ktn);                        /* prefetch next K tile */     \
        _Pragma("unroll")                                                      \
        for (int g = 0; g < 4; ++g) {                                          \
            floatx4 s0 = {}, s1 = {};                                          \
            __builtin_amdgcn_s_setprio(1);                                     \
            s0 = __builtin_amdgcn_mfma_f32_16x16x32_bf16(CUR[0][0], qf[g][0], s0, 0, 0, 0); \
            s0 = __builtin_amdgcn_mfma_f32_16x16x32_bf16(CUR[0][1], qf[g][1], s0, 0, 0, 0); \
            s1 = __builtin_amdgcn_mfma_f32_16x16x32_bf16(CUR[1][0], qf[g][0], s1, 0, 0, 0); \
            s1 = __builtin_amdgcn_mfma_f32_16x16x32_bf16(CUR[1][1], qf[g][1], s1, 0, 0, 0); \
            __builtin_amdgcn_s_setprio(0);                                     \
            _Pragma("unroll")                                                  \
            for (int r = 0; r < 4; ++r) {                                      \
                s0[r] = __builtin_amdgcn_exp2f(s0[r]);                         \
                s1[r] = __builtin_amdgcn_exp2f(s1[r]);                         \
            }                                                                  \
            l_part[g] += ((s0[0] + s0[1]) + (s0[2] + s0[3]))                   \
                       + ((s1[0] + s1[1]) + (s1[2] + s1[3]));                  \
            /* pack: w0,w1 = nt0 keys (4Q..4Q+3); w2,w3 = nt1 */               \
            unsigned w0 = pkbf(s0[0], s0[1]);                                  \
            unsigned w1 = pkbf(s0[2], s0[3]);                                  \
            unsigned w2 = pkbf(s1[0], s1[1]);                                  \
            unsigned w3 = pkbf(s1[2], s1[3]);                                  \
            /* butterfly T1: exchange across lane bit 32 (quad bit q1) */      \
            unsigned t0 = q1 ? w0 : w2, t1 = q1 ? w1 : w3;                     \
            unsigned r0 = (unsigned)__shfl_xor((int)t0, 32, 64);               \
            unsigned r1 = (unsigned)__shfl_xor((int)t1, 32, 64);               \
            unsigned m0 = q1 ? r0 : w0, m1 = q1 ? r1 : w1;                     \
            unsigned m2 = q1 ? w2 : r0, m3 = q1 ? w3 : r1;                     \
            /* butterfly T2: exchange across lane bit 16 (quad bit q0) */      \
            unsigned u0 = q0b ? m0 : m2, u1 = q0b ? m1 : m3;                   \
            unsigned x0 = (unsigned)__shfl_xor((int)u0, 16, 64);               \
            unsigned x1 = (unsigned)__shfl_xor((int)u1, 16, 64);               \
            union { unsigned u[4]; short8 s8; } pu;                            \
            pu.u[0] = q0b ? x0 : m0; pu.u[1] = q0b ? x1 : m1;                  \
            pu.u[2] = q0b ? m2 : x0; pu.u[3] = q0b ? m3 : x1;                  \
            const short8 pf = pu.s8;   /* A-frag: P[q=l15][keys 8*quad..+7] */ \
            __builtin_amdgcn_s_setprio(1);                                     \
            _Pragma("unroll")                                                  \
            for (int dt = 0; dt < 4; ++dt)                                     \
                o[g][dt] = __builtin_amdgcn_mfma_f32_16x16x32_bf16(            \
                    pf, vf[dt], o[g][dt], 0, 0, 0);                            \
            __builtin_amdgcn_s_setprio(0);                                     \
        }                                                                      \
    } while (0)

    LOADK(kfA, 0);
    for (int kt = 0; kt < 64; kt += 2) {
        TILE(kfA, kfB, kt, kt + 1);
        TILE(kfB, kfA, kt + 1, (kt + 2 < 64) ? (kt + 2) : 0);
    }
#undef TILE
#undef LOADK

    // softmax denominator: quads hold disjoint key subsets -> reduce over quads
#pragma unroll
    for (int g = 0; g < 4; ++g) {
        float lsum = l_part[g];
        lsum += __shfl_xor(lsum, 16, 64);
        lsum += __shfl_xor(lsum, 32, 64);
        const float inv = 1.0f / lsum;   // all lanes: denom for q-row = g*16+l15
#pragma unroll
        for (int r = 0; r < 4; ++r) {
            const float invq = __shfl(inv, quad * 4 + r, 64);  // denom of this O row
            const int row = qbase + g * 16 + quad * 4 + r;
#pragma unroll
            for (int dt = 0; dt < 4; ++dt)
                attn_out[((size_t)b * N_ + row) * DIM_ + h * DH_ + dt * 16 + l15] =
                    f2bf(o[g][dt][r] * invq);
        }
    }
}

// ---------------------------------------------------------------------------
extern "C" void kernel_launch(void* const* d_in, const int* in_sizes, int n_in,
                              void* d_out, int out_size, void* d_ws, size_t ws_size,
                              hipStream_t stream) {
    const float* x      = (const float*)d_in[0];
    const float* qkv_w  = (const float*)d_in[1];
    const float* qkv_b  = (const float*)d_in[2];
    const float* proj_w = (const float*)d_in[3];
    const float* proj_b = (const float*)d_in[4];
    const float* temp   = (const float*)d_in[5];
    const float* eps    = (const float*)d_in[6];
    float* out = (float*)d_out;

    unsigned short* qb   = (unsigned short*)d_ws;          // [B,H,N,DH]
    unsigned short* kb   = qb + QKV_ELEMS;                 // [B,H,N,DH]
    unsigned short* vb   = kb + QKV_ELEMS;                 // [B,H,DH,N] (transposed)
    unsigned short* xb   = vb + QKV_ELEMS;                 // x bf16
    unsigned short* wqb  = xb + QKV_ELEMS;                 // qkv_w bf16
    unsigned short* pwb  = wqb + (size_t)3 * DIM_ * DIM_;  // proj_w bf16
    unsigned short* attn = pwb + (size_t)DIM_ * DIM_;      // attn bf16 [B,N,DIM]

    dim3 blk(256);
    f32_to_bf16_kernel<<<dim3(8388608 / 8 / 256), blk, 0, stream>>>(x, xb, 8388608 / 8);
    f32_to_bf16_kernel<<<dim3(3145728 / 8 / 256), blk, 0, stream>>>(qkv_w, wqb, 3145728 / 8);
    f32_to_bf16_kernel<<<dim3(1048576 / 8 / 256), blk, 0, stream>>>(proj_w, pwb, 1048576 / 8);

    gemm_qkv_bf16<<<dim3(24, 64), blk, 0, stream>>>(xb, wqb, qkv_b, eps, temp,
                                                    qb, kb, vb);
    attn_kernel<<<dim3(512), dim3(256), 0, stream>>>(qb, kb, vb, attn);
    gemm_proj_bf16<<<dim3(8, 64), blk, 0, stream>>>(attn, pwb, proj_b, out);
}

// Round 4
// 386.530 us; speedup vs baseline: 1.0338x; 1.0232x over previous
//
#include <hip/hip_runtime.h>
#include <math.h>

#define B_   4
#define N_   2048
#define DIM_ 1024
#define H_   16
#define DH_  64
#define M_   (B_ * N_)          // 8192
#define QKV_ELEMS ((size_t)B_ * H_ * N_ * DH_)   // 8388608

typedef __attribute__((ext_vector_type(8))) short short8;   // 8 bf16 (4 VGPRs)
typedef __attribute__((ext_vector_type(4))) float floatx4;  // MFMA C/D frag

// round-to-nearest-even float -> bf16 bits
static __device__ inline unsigned short f2bf(float f) {
    union { float f; unsigned u; } v; v.f = f;
    unsigned r = (v.u + 0x7fffu + ((v.u >> 16) & 1u)) >> 16;
    return (unsigned short)r;
}

// pack two f32 -> two bf16 (round-half-up)
static __device__ inline unsigned pkbf(float a, float b) {
    unsigned ua = (__float_as_uint(a) + 0x8000u) >> 16;
    unsigned ub = (__float_as_uint(b) + 0x8000u) & 0xffff0000u;
    return ua | ub;
}

// async global->LDS, 16 B per lane. lds dest = wave-uniform base + lane*16.
static __device__ inline void async_copy16(const void* g, void* l) {
    __builtin_amdgcn_global_load_lds(
        (const __attribute__((address_space(1))) unsigned int*)g,
        (__attribute__((address_space(3))) unsigned int*)l, 16, 0, 0);
}

// ---------------------------------------------------------------------------
// Kernel 0: fp32 -> bf16 convert
// ---------------------------------------------------------------------------
__global__ __launch_bounds__(256) void f32_to_bf16_kernel(
    const float* __restrict__ src, unsigned short* __restrict__ dst, int n8)
{
    int i = blockIdx.x * 256 + threadIdx.x;
    if (i >= n8) return;
    float4 a = ((const float4*)src)[i * 2];
    float4 b = ((const float4*)src)[i * 2 + 1];
    short8 o;
    o[0] = f2bf(a.x); o[1] = f2bf(a.y); o[2] = f2bf(a.z); o[3] = f2bf(a.w);
    o[4] = f2bf(b.x); o[5] = f2bf(b.y); o[6] = f2bf(b.z); o[7] = f2bf(b.w);
    *(short8*)(dst + (size_t)i * 8) = o;
}

// ---------------------------------------------------------------------------
// bf16 MFMA GEMM core (m97 structure): C[m,n] = sum_k A[m,k]*B[n,k]
// ---------------------------------------------------------------------------
#define GEMM_BODY(Aptr, Bptr, K)                                               \
    __shared__ unsigned short As[128 * 32];                                    \
    __shared__ unsigned short Bs[128 * 32];                                    \
    const int tid  = threadIdx.x;                                              \
    const int lane = tid & 63;                                                 \
    const int wv   = tid >> 6;                                                 \
    const int l15  = lane & 15, quad = lane >> 4;                              \
    const int wrow = (wv >> 1) * 64, wcol = (wv & 1) * 64;                     \
    const int m0 = blockIdx.y * 128, n0 = blockIdx.x * 128;                    \
    const int lrow = lane >> 2;                                                \
    const int lkc  = (lane & 3) * 8;                                           \
    const unsigned short* ga0 = Aptr + (size_t)(m0 + wv * 32 + lrow) * K + lkc;\
    const unsigned short* ga1 = ga0 + (size_t)16 * K;                          \
    const unsigned short* gb0 = Bptr + (size_t)(n0 + wv * 32 + lrow) * K + lkc;\
    const unsigned short* gb1 = gb0 + (size_t)16 * K;                          \
    unsigned short* lA0 = &As[wv * 1024];                                      \
    unsigned short* lA1 = lA0 + 512;                                           \
    unsigned short* lB0 = &Bs[wv * 1024];                                      \
    unsigned short* lB1 = lB0 + 512;                                           \
    floatx4 acc[4][4] = {};                                                    \
    for (int k0 = 0; k0 < K; k0 += 32) {                                       \
        __syncthreads();                                                       \
        async_copy16(ga0 + k0, lA0);                                           \
        async_copy16(ga1 + k0, lA1);                                           \
        async_copy16(gb0 + k0, lB0);                                           \
        async_copy16(gb1 + k0, lB1);                                           \
        __syncthreads();                                                       \
        short8 af[4], bf[4];                                                   \
        _Pragma("unroll")                                                      \
        for (int mt = 0; mt < 4; ++mt)                                         \
            af[mt] = *(const short8*)&As[(wrow + mt * 16 + l15) * 32 + quad * 8];\
        _Pragma("unroll")                                                      \
        for (int nt = 0; nt < 4; ++nt)                                         \
            bf[nt] = *(const short8*)&Bs[(wcol + nt * 16 + l15) * 32 + quad * 8];\
        _Pragma("unroll")                                                      \
        for (int mt = 0; mt < 4; ++mt)                                         \
            _Pragma("unroll")                                                  \
            for (int nt = 0; nt < 4; ++nt)                                     \
                acc[mt][nt] = __builtin_amdgcn_mfma_f32_16x16x32_bf16(         \
                    af[mt], bf[nt], acc[mt][nt], 0, 0, 0);                     \
    }

// ---------------------------------------------------------------------------
// Kernel 1: QKV projection, bf16 MFMA. M=8192, N=3072, K=1024.
// Epilogue: q gets noise then *0.125*log2e (attn scale + exp2 fold), bf16.
// k in [B,H,N,DH]; v stored PERMUTED for the attention PV B-fragment:
//   v[bh][(kt*64+dd)*32 + a*8 + j] = V[kt*32 + kappa(a,j)][dd],
//   kappa(a,j) = (j<4 ? 4a+j : 16+4a+j-4)  -- folds the QK->PV key
//   permutation into storage, so attn needs NO butterfly and its V loads
//   are 1KB-contiguous per instruction.
// ---------------------------------------------------------------------------
__global__ __launch_bounds__(256) void gemm_qkv_bf16(
    const unsigned short* __restrict__ A, const unsigned short* __restrict__ Bm,
    const float* __restrict__ bias, const float* __restrict__ eps,
    const float* __restrict__ temp,
    unsigned short* __restrict__ qb, unsigned short* __restrict__ kb,
    unsigned short* __restrict__ vb)
{
    GEMM_BODY(A, Bm, 1024)

    const float sig = 1.0f / (1.0f + __expf(-temp[0]));
    const float qscale = 0.125f * 1.44269504f;   // 1/sqrt(DH) * log2(e)
#pragma unroll
    for (int mt = 0; mt < 4; ++mt) {
#pragma unroll
        for (int r = 0; r < 4; ++r) {
            const int m  = m0 + wrow + mt * 16 + quad * 4 + r;
            const int b  = m >> 11;
            const int nn = m & 2047;
#pragma unroll
            for (int nt = 0; nt < 4; ++nt) {
                const int n = n0 + wcol + nt * 16 + l15;
                float val = acc[mt][nt][r] + bias[n];
                const int which = n >> 10;   // 0=q 1=k 2=v
                const int d  = n & 1023;
                const int h  = d >> 6;
                const int dd = d & 63;
                const size_t bh = (size_t)(b * H_ + h);
                if (which == 0) {
                    const size_t idx = (bh * N_ + nn) * DH_ + dd;
                    qb[idx] = f2bf((val + eps[idx] * sig) * qscale);
                } else if (which == 1) {
                    kb[(bh * N_ + nn) * DH_ + dd] = f2bf(val);
                } else {
                    // permuted V: kt tile, key-in-tile -> (a, j) slot
                    const int kt  = nn >> 5;
                    const int k32 = nn & 31;
                    const int lo  = k32 & 15;
                    const int a   = lo >> 2;
                    const int j   = ((k32 >> 4) << 2) + (lo & 3);
                    vb[bh * (size_t)(N_ * DH_) +
                       ((size_t)(kt * 64 + dd) * 4 + a) * 8 + j] = f2bf(val);
                }
            }
        }
    }
}

// ---------------------------------------------------------------------------
// Kernel 3: output projection, bf16 MFMA. M=8192, N=1024, K=1024. fp32 out.
// ---------------------------------------------------------------------------
__global__ __launch_bounds__(256) void gemm_proj_bf16(
    const unsigned short* __restrict__ A, const unsigned short* __restrict__ Bm,
    const float* __restrict__ bias, float* __restrict__ out)
{
    GEMM_BODY(A, Bm, 1024)

#pragma unroll
    for (int mt = 0; mt < 4; ++mt) {
#pragma unroll
        for (int r = 0; r < 4; ++r) {
            const int m = m0 + wrow + mt * 16 + quad * 4 + r;
#pragma unroll
            for (int nt = 0; nt < 4; ++nt) {
                const int n = n0 + wcol + nt * 16 + l15;
                out[(size_t)m * 1024 + n] = acc[mt][nt][r] + bias[n];
            }
        }
    }
}

// ---------------------------------------------------------------------------
// Kernel 2: flash attention v4.1 — v4 with the normalization fix.
//  (Round-3 fail: store used inv [denominator of q-row l15] instead of
//   invq [denominator of the stored row quad*4+r]; absmax 6e-3 matched
//   the mixed-nearby-denominator signature. Structure unchanged.)
//  - zero LDS, zero barriers; K/V L2-resident, direct-to-register
//  - rolling 1-deep pipeline: QK(unit u+1) before softmax+PV(u), named
//    score regs sa/sb (rule #20), 2-tile unrolled body, K/V dbuf by name
//  - V stored in PV-fragment order (kappa folded into gemm_qkv layout):
//    no butterfly, P-frag = 4 pkbf words, V loads 1KB-contiguous
// ---------------------------------------------------------------------------
__global__ __launch_bounds__(256, 2) void attn_kernel(
    const unsigned short* __restrict__ qb, const unsigned short* __restrict__ kb,
    const unsigned short* __restrict__ vt, unsigned short* __restrict__ attn_out)
{
    const int tid  = threadIdx.x;
    const int lane = tid & 63;
    const int wv   = tid >> 6;      // 0..3, independent waves (no barriers)
    const int l15  = lane & 15;
    const int quad = lane >> 4;

    // XCD-aware swizzle: 512 blocks = 8 XCDs x 64; 8 consecutive bh per XCD
    const int f  = blockIdx.x;
    const int L  = (f & 7) * 64 + (f >> 3);
    const int bh = L >> 3;
    const int b  = bh >> 4, h = bh & 15;
    const int qbase = (L & 7) * 256 + wv * 64;   // 64 q-rows per wave

    const unsigned short* kb_bh = kb + (size_t)bh * N_ * DH_;
    const unsigned short* vt_bh = vt + (size_t)bh * N_ * DH_;

    // Q fragments: 4 groups of 16 rows x (d0-31, d32-63). (q pre-scaled.)
    short8 qf[4][2];
#pragma unroll
    for (int g = 0; g < 4; ++g) {
        const unsigned short* qp =
            qb + ((size_t)bh * N_ + qbase + g * 16 + l15) * DH_;
        qf[g][0] = *(const short8*)(qp + quad * 8);
        qf[g][1] = *(const short8*)(qp + 32 + quad * 8);
    }

    floatx4 o[4][4] = {};
    float l_part[4] = {0.f, 0.f, 0.f, 0.f};

    // per-lane fragment base pointers
    const unsigned short* kA = kb_bh + (size_t)l15 * DH_ + quad * 8;

    short8 kfA[2][2], kfB[2][2], vfA[4], vfB[4];
    floatx4 sa0, sa1, sb0, sb1;

#define LOADK(DST, ktn)                                                        \
    do {                                                                       \
        _Pragma("unroll")                                                      \
        for (int nt = 0; nt < 2; ++nt)                                         \
            _Pragma("unroll")                                                  \
            for (int hh = 0; hh < 2; ++hh)                                     \
                DST[nt][hh] = *(const short8*)(                                \
                    kA + (size_t)((ktn) * 32 + nt * 16) * DH_ + hh * 32);      \
    } while (0)

#define LOADV(DST, ktn)                                                        \
    do {                                                                       \
        _Pragma("unroll")                                                      \
        for (int dt = 0; dt < 4; ++dt)                                         \
            DST[dt] = *(const short8*)(vt_bh +                                 \
                ((size_t)((ktn) * 64 + dt * 16 + l15) * 4 + quad) * 8);        \
    } while (0)

#define QK(S0, S1, KF, g)                                                      \
    do {                                                                       \
        floatx4 z0 = {}, z1 = {};                                              \
        z0 = __builtin_amdgcn_mfma_f32_16x16x32_bf16(KF[0][0], qf[g][0], z0, 0, 0, 0); \
        z0 = __builtin_amdgcn_mfma_f32_16x16x32_bf16(KF[0][1], qf[g][1], z0, 0, 0, 0); \
        z1 = __builtin_amdgcn_mfma_f32_16x16x32_bf16(KF[1][0], qf[g][0], z1, 0, 0, 0); \
        z1 = __builtin_amdgcn_mfma_f32_16x16x32_bf16(KF[1][1], qf[g][1], z1, 0, 0, 0); \
        S0 = z0; S1 = z1;                                                      \
    } while (0)

#define SPV(S0, S1, VF, g)                                                     \
    do {                                                                       \
        _Pragma("unroll")                                                      \
        for (int r = 0; r < 4; ++r) {                                          \
            S0[r] = __builtin_amdgcn_exp2f(S0[r]);                             \
            S1[r] = __builtin_amdgcn_exp2f(S1[r]);                             \
        }                                                                      \
        l_part[g] += ((S0[0] + S0[1]) + (S0[2] + S0[3]))                       \
                   + ((S1[0] + S1[1]) + (S1[2] + S1[3]));                      \
        union { unsigned u[4]; short8 s8; } pu;                                \
        pu.u[0] = pkbf(S0[0], S0[1]); pu.u[1] = pkbf(S0[2], S0[3]);            \
        pu.u[2] = pkbf(S1[0], S1[1]); pu.u[3] = pkbf(S1[2], S1[3]);            \
        o[g][0] = __builtin_amdgcn_mfma_f32_16x16x32_bf16(pu.s8, VF[0], o[g][0], 0, 0, 0); \
        o[g][1] = __builtin_amdgcn_mfma_f32_16x16x32_bf16(pu.s8, VF[1], o[g][1], 0, 0, 0); \
        o[g][2] = __builtin_amdgcn_mfma_f32_16x16x32_bf16(pu.s8, VF[2], o[g][2], 0, 0, 0); \
        o[g][3] = __builtin_amdgcn_mfma_f32_16x16x32_bf16(pu.s8, VF[3], o[g][3], 0, 0, 0); \
    } while (0)

    LOADK(kfA, 0); LOADV(vfA, 0);
    LOADK(kfB, 1); LOADV(vfB, 1);
    QK(sa0, sa1, kfA, 0);

    for (int kt = 0; kt < 64; kt += 2) {
        const int t2 = (kt + 2) & 63;   // wraps harmlessly on last iter
        const int t3 = (kt + 3) & 63;
        // ---- tile kt (K=kfA, V=vfA) ----
        QK(sb0, sb1, kfA, 1);  SPV(sa0, sa1, vfA, 0);
        QK(sa0, sa1, kfA, 2);  SPV(sb0, sb1, vfA, 1);
        QK(sb0, sb1, kfA, 3);  SPV(sa0, sa1, vfA, 2);
        LOADK(kfA, t2);                      // kfA dead after QK g3
        QK(sa0, sa1, kfB, 0);  SPV(sb0, sb1, vfA, 3);
        LOADV(vfA, t2);                      // vfA dead after SPV g3
        // ---- tile kt+1 (K=kfB, V=vfB) ----
        QK(sb0, sb1, kfB, 1);  SPV(sa0, sa1, vfB, 0);
        QK(sa0, sa1, kfB, 2);  SPV(sb0, sb1, vfB, 1);
        QK(sb0, sb1, kfB, 3);  SPV(sa0, sa1, vfB, 2);
        LOADK(kfB, t3);                      // kfB dead after QK g3
        QK(sa0, sa1, kfA, 0);  SPV(sb0, sb1, vfB, 3);   // QK of tile kt+2
        LOADV(vfB, t3);                      // vfB dead after SPV g3
    }
    // dangling QK (wrapped tile) is discarded.
#undef QK
#undef SPV
#undef LOADK
#undef LOADV

    // softmax denominator: quads hold disjoint key subsets -> reduce over quads
#pragma unroll
    for (int g = 0; g < 4; ++g) {
        float lsum = l_part[g];
        lsum += __shfl_xor(lsum, 16, 64);
        lsum += __shfl_xor(lsum, 32, 64);
        const float inv = 1.0f / lsum;   // all lanes: denom for q-row = g*16+l15
#pragma unroll
        for (int r = 0; r < 4; ++r) {
            const float invq = __shfl(inv, quad * 4 + r, 64);  // denom of this O row
            const int row = qbase + g * 16 + quad * 4 + r;
#pragma unroll
            for (int dt = 0; dt < 4; ++dt)
                attn_out[((size_t)b * N_ + row) * DIM_ + h * DH_ + dt * 16 + l15] =
                    f2bf(o[g][dt][r] * invq);
        }
    }
}

// ---------------------------------------------------------------------------
extern "C" void kernel_launch(void* const* d_in, const int* in_sizes, int n_in,
                              void* d_out, int out_size, void* d_ws, size_t ws_size,
                              hipStream_t stream) {
    const float* x      = (const float*)d_in[0];
    const float* qkv_w  = (const float*)d_in[1];
    const float* qkv_b  = (const float*)d_in[2];
    const float* proj_w = (const float*)d_in[3];
    const float* proj_b = (const float*)d_in[4];
    const float* temp   = (const float*)d_in[5];
    const float* eps    = (const float*)d_in[6];
    float* out = (float*)d_out;

    unsigned short* qb   = (unsigned short*)d_ws;          // [B,H,N,DH]
    unsigned short* kb   = qb + QKV_ELEMS;                 // [B,H,N,DH]
    unsigned short* vb   = kb + QKV_ELEMS;                 // [B,H] PV-frag order
    unsigned short* xb   = vb + QKV_ELEMS;                 // x bf16
    unsigned short* wqb  = xb + QKV_ELEMS;                 // qkv_w bf16
    unsigned short* pwb  = wqb + (size_t)3 * DIM_ * DIM_;  // proj_w bf16
    unsigned short* attn = pwb + (size_t)DIM_ * DIM_;      // attn bf16 [B,N,DIM]

    dim3 blk(256);
    f32_to_bf16_kernel<<<dim3(8388608 / 8 / 256), blk, 0, stream>>>(x, xb, 8388608 / 8);
    f32_to_bf16_kernel<<<dim3(3145728 / 8 / 256), blk, 0, stream>>>(qkv_w, wqb, 3145728 / 8);
    f32_to_bf16_kernel<<<dim3(1048576 / 8 / 256), blk, 0, stream>>>(proj_w, pwb, 1048576 / 8);

    gemm_qkv_bf16<<<dim3(24, 64), blk, 0, stream>>>(xb, wqb, qkv_b, eps, temp,
                                                    qb, kb, vb);
    attn_kernel<<<dim3(512), dim3(256), 0, stream>>>(qb, kb, vb, attn);
    gemm_proj_bf16<<<dim3(8, 64), blk, 0, stream>>>(attn, pwb, proj_b, out);
}